// Round 2
// baseline (229.707 us; speedup 1.0000x reference)
//
#include <hip/hip_runtime.h>
#include <hip/hip_bf16.h>
#include <stdint.h>

typedef __bf16 bf16;
typedef __bf16 bf16x8 __attribute__((ext_vector_type(8)));
typedef float f32x4 __attribute__((ext_vector_type(4)));
typedef float f32x16 __attribute__((ext_vector_type(16)));

#define HIDDEN 1024
#define HEADS  16
#define HD     64
#define SEQ    2048
#define BATCH  2
#define NTOK   (BATCH*SEQ)
#define E3     (3*HIDDEN)

// softmax scale 1/8 with log2(e) folded in, applied to Q at QKV-GEMM epilogue
#define QSCALE (0.125f * 1.44269504088896f)

static __device__ __forceinline__ uint32_t pkbf(float a, float b) {
  union { bf16 h[2]; uint32_t u; } x;
  x.h[0] = (bf16)a; x.h[1] = (bf16)b;
  return x.u;
}

// ---------------- f32 -> bf16 convert of x, w_qkv, w_out ----------------
__global__ __launch_bounds__(256) void k_convert(
    const float* __restrict__ x, const float* __restrict__ wqkv, const float* __restrict__ wout,
    bf16* __restrict__ xb, bf16* __restrict__ wqkvb, bf16* __restrict__ woutb)
{
  const int NX = NTOK*HIDDEN/4, NW = E3*HIDDEN/4;
  int i = blockIdx.x*256 + threadIdx.x;
  const float4* s; bf16* d; int o;
  if (i < NX)            { s=(const float4*)x;    d=xb;    o=i; }
  else if (i < NX+NW)    { s=(const float4*)wqkv; d=wqkvb; o=i-NX; }
  else                   { s=(const float4*)wout; d=woutb; o=i-NX-NW; }
  float4 v = s[o];
  union { bf16 b[4]; uint2 u; } p;
  p.b[0]=(bf16)v.x; p.b[1]=(bf16)v.y; p.b[2]=(bf16)v.z; p.b[3]=(bf16)v.w;
  *(uint2*)(d + (size_t)o*4) = p.u;
}

// ---------------- bf16 GEMM  C[M,N] = A[M,K] * B[N,K]^T ----------------
// EPI=0: scatter to Q/K/V head layout (Q scaled by QSCALE).  EPI=1: f32 out.
// BM: 128 (acc 4x4) or 64 (acc 2x4).  BN fixed 128, BK 32.
template<int EPI, int BM>
__global__ __launch_bounds__(256) void k_gemm(
    const bf16* __restrict__ A, const bf16* __restrict__ B,
    bf16* __restrict__ Oq, bf16* __restrict__ Ok, bf16* __restrict__ Ov,
    float* __restrict__ Of, int M, int N, int K, int nbn)
{
  constexpr int MI = BM/32;            // m-fragments per wave
  __shared__ bf16 As[BM*32];
  __shared__ bf16 Bs[128*32];
  const int t = threadIdx.x;
  const int lane = t & 63;
  const int w = t >> 6;
  const int g = lane >> 4;
  const int l15 = lane & 15;
  const int wm = (w >> 1) * (BM/2), wn = (w & 1) * 64;
  const int bm = blockIdx.x / nbn, bn = blockIdx.x % nbn;
  const int brow = bm*BM, bcol = bn*128;

  f32x4 acc[MI][4];
  #pragma unroll
  for (int mi=0;mi<MI;mi++)
    #pragma unroll
    for (int ni=0;ni<4;ni++)
      #pragma unroll
      for (int r=0;r<4;r++) acc[mi][ni][r] = 0.f;

  const int nk = K >> 5;
  for (int kt = 0; kt < nk; ++kt) {
    // stage A (BM*4 chunks of 16B) and B (512 chunks); LDS linear, chunk ch -> row=ch>>2, part=ch&3
    if constexpr (BM == 128) {
      int ch = w*128 + lane;
      const bf16* ga = A + (size_t)(brow + (ch>>2))*K + kt*32 + (ch&3)*8;
      __builtin_amdgcn_global_load_lds((const uint32_t*)ga, (uint32_t*)(As + (w*128)*8), 16, 0, 0);
      int ch2 = ch + 64;
      const bf16* ga2 = A + (size_t)(brow + (ch2>>2))*K + kt*32 + (ch2&3)*8;
      __builtin_amdgcn_global_load_lds((const uint32_t*)ga2, (uint32_t*)(As + (w*128+64)*8), 16, 0, 0);
    } else {
      int ch = w*64 + lane;
      const bf16* ga = A + (size_t)(brow + (ch>>2))*K + kt*32 + (ch&3)*8;
      __builtin_amdgcn_global_load_lds((const uint32_t*)ga, (uint32_t*)(As + (w*64)*8), 16, 0, 0);
    }
    {
      int ch = w*128 + lane;
      const bf16* gb = B + (size_t)(bcol + (ch>>2))*K + kt*32 + (ch&3)*8;
      __builtin_amdgcn_global_load_lds((const uint32_t*)gb, (uint32_t*)(Bs + (w*128)*8), 16, 0, 0);
      int ch2 = ch + 64;
      const bf16* gb2 = B + (size_t)(bcol + (ch2>>2))*K + kt*32 + (ch2&3)*8;
      __builtin_amdgcn_global_load_lds((const uint32_t*)gb2, (uint32_t*)(Bs + (w*128+64)*8), 16, 0, 0);
    }
    __syncthreads();
    bf16x8 af[MI], bfr[4];
    #pragma unroll
    for (int mi=0;mi<MI;mi++) af[mi]  = *(const bf16x8*)(As + (wm + mi*16 + l15)*32 + g*8);
    #pragma unroll
    for (int ni=0;ni<4;ni++) bfr[ni] = *(const bf16x8*)(Bs + (wn + ni*16 + l15)*32 + g*8);
    #pragma unroll
    for (int mi=0;mi<MI;mi++)
      #pragma unroll
      for (int ni=0;ni<4;ni++)
        acc[mi][ni] = __builtin_amdgcn_mfma_f32_16x16x32_bf16(af[mi], bfr[ni], acc[mi][ni], 0, 0, 0);
    __syncthreads();
  }

  // epilogue: D layout: row m = 4*g + reg (+16*mi +wm), col n = l15 (+16*ni +wn)
  #pragma unroll
  for (int mi=0;mi<MI;mi++) {
    #pragma unroll
    for (int ni=0;ni<4;ni++) {
      #pragma unroll
      for (int r=0;r<4;r++) {
        float val = acc[mi][ni][r];
        int m = brow + wm + mi*16 + 4*g + r;
        int e = bcol + wn + ni*16 + l15;
        if (EPI == 0) {
          int part = e >> 10, we = e & 1023;
          int hh = we >> 6, dd = we & 63;
          int b = m >> 11, sb = m & 2047;
          size_t idx = (((size_t)b*HEADS + hh)*SEQ + sb)*HD + dd;
          if (part == 0)      Oq[idx] = (bf16)(val * QSCALE);
          else if (part == 1) Ok[idx] = (bf16)val;
          else                Ov[idx] = (bf16)val;
        } else {
          Of[(size_t)m*HIDDEN + e] = val;
        }
      }
    }
  }
}

// ---------------- flash attention, swapped QK^T, 32x32x16 MFMA ----------------
// grid: 32 bh * 16 qblocks; block: 4 waves, each wave owns 32 q rows.
// Double-buffered K/V tiles + async-stage split (issue i+1 loads before compute i).
__global__ __launch_bounds__(256) void k_attn(
    const bf16* __restrict__ Qg, const bf16* __restrict__ Kg, const bf16* __restrict__ Vg,
    bf16* __restrict__ Og)
{
  __shared__ bf16 Kl[2][64*64];   // [kv][d], rows XOR-swizzled by ((row&7)<<4) bytes
  __shared__ bf16 Vt[2][64*64];   // [d][kv], rows XOR-swizzled by ((row&7)<<4) bytes
  const int t = threadIdx.x;
  const int lane = t & 63;
  const int w = t >> 6;
  const int h = lane >> 5;       // wave half
  const int q = lane & 31;       // this lane's q row (within wave tile)
  const int bh = blockIdx.x >> 4;
  const int qb = blockIdx.x & 15;
  const int q0 = qb*128 + w*32;
  const size_t bhS = (size_t)bh * SEQ * HD;

  // Q fragments (B-operand), hoisted: k-slot (h,j) -> d = 16s + 8h + j
  bf16x8 qf[4];
  const bf16* qrow = Qg + bhS + (size_t)(q0 + q)*HD;
  #pragma unroll
  for (int s=0;s<4;s++) qf[s] = *(const bf16x8*)(qrow + 16*s + 8*h);

  f32x16 ot[2];
  #pragma unroll
  for (int mf=0;mf<2;mf++)
    #pragma unroll
    for (int r=0;r<16;r++) ot[mf][r]=0.f;
  float mrun = -3.0e38f, lrun = 0.f;

  const int kvv0 = (t & 31)*2, dd0 = (t>>5)*8;

  auto stageK = [&](int it, int buf) {
    int ch = w*128 + lane;
    int row = ch>>3, o16 = ch&7;
    const bf16* gp = Kg + bhS + (size_t)(it*64+row)*HD + ((o16*8) ^ ((row&7)*8));
    __builtin_amdgcn_global_load_lds((const uint32_t*)gp, (uint32_t*)(&Kl[buf][0] + (size_t)(w*128)*8), 16, 0, 0);
    int ch2 = ch + 64;
    int row2 = ch2>>3, o16b = ch2&7;
    const bf16* gp2 = Kg + bhS + (size_t)(it*64+row2)*HD + ((o16b*8) ^ ((row2&7)*8));
    __builtin_amdgcn_global_load_lds((const uint32_t*)gp2, (uint32_t*)(&Kl[buf][0] + (size_t)(w*128+64)*8), 16, 0, 0);
  };
  auto loadV = [&](int it, uint4& va, uint4& vb) {
    const bf16* vg = Vg + bhS + (size_t)(it*64 + kvv0)*HD + dd0;
    va = *(const uint4*)vg;
    vb = *(const uint4*)(vg + HD);
  };
  auto writeVt = [&](uint4 va, uint4 vb, int buf) {
    const uint32_t* pa = (const uint32_t*)&va;
    const uint32_t* pb = (const uint32_t*)&vb;
    #pragma unroll
    for (int jj=0;jj<8;jj++) {
      int dd = dd0 + jj;
      uint32_t lo = (jj&1) ? (pa[jj>>1] >> 16) : (pa[jj>>1] & 0xffffu);
      uint32_t hi = (jj&1) ? (pb[jj>>1] >> 16) : (pb[jj>>1] & 0xffffu);
      int byte = (dd*128 + kvv0*2) ^ ((dd&7)<<4);
      *(uint32_t*)((char*)&Vt[buf][0] + byte) = lo | (hi<<16);
    }
  };

  // prologue: tile 0 into buffer 0
  {
    uint4 va, vb;
    stageK(0, 0);
    loadV(0, va, vb);
    writeVt(va, vb, 0);
  }
  __syncthreads();   // drains vmcnt (K gload_lds) + lgkm

  const int NT = SEQ/64;
  for (int it=0; it<NT; ++it) {
    const int cur = it & 1;
    const bool pre = (it+1) < NT;
    uint4 na, nb;
    if (pre) { stageK(it+1, cur^1); loadV(it+1, na, nb); }

    // QK^T swapped: sf = K * Q^T  -> lane has q = lane&31, kv along regs
    f32x16 sf[2];
    #pragma unroll
    for (int mf=0;mf<2;mf++)
      #pragma unroll
      for (int r=0;r<16;r++) sf[mf][r]=0.f;
    #pragma unroll
    for (int s=0;s<4;s++) {
      #pragma unroll
      for (int mf=0;mf<2;mf++) {
        int row = mf*32 + q;
        int byte = (row*128 + 32*s + 16*h) ^ ((row&7)<<4);
        bf16x8 kf = *(const bf16x8*)((const char*)&Kl[cur][0] + byte);
        sf[mf] = __builtin_amdgcn_mfma_f32_32x32x16_bf16(kf, qf[s], sf[mf], 0,0,0);
      }
    }

    // online softmax in log2 domain (Q pre-scaled by log2e/8); defer-max THR=8
    float mx[16];
    #pragma unroll
    for (int r=0;r<16;r++) mx[r] = fmaxf(sf[0][r], sf[1][r]);
    #pragma unroll
    for (int dstep=8; dstep; dstep>>=1)
      #pragma unroll
      for (int r=0;r<8;r++) if (r < dstep) mx[r] = fmaxf(mx[r], mx[r+dstep]);
    float pm = fmaxf(mx[0], __shfl_xor(mx[0], 32, 64));

    if (__any(pm - mrun > 8.f)) {
      float mnew = fmaxf(mrun, pm);
      float alpha = exp2f(mrun - mnew);
      lrun *= alpha;
      #pragma unroll
      for (int mf=0;mf<2;mf++)
        #pragma unroll
        for (int r=0;r<16;r++) ot[mf][r] *= alpha;
      mrun = mnew;
    }
    float rs = 0.f;
    #pragma unroll
    for (int mf=0;mf<2;mf++)
      #pragma unroll
      for (int r=0;r<16;r++) { float p = exp2f(sf[mf][r]-mrun); sf[mf][r]=p; rs += p; }
    rs += __shfl_xor(rs, 32, 64);
    lrun += rs;

    // pack P^T (B-operand) + PV: O^T += V^T * P^T
    #pragma unroll
    for (int s=0;s<4;s++) {
      const int f = s>>1, bb = 8*(s&1);
      uint32_t g0A = pkbf(sf[f][bb+0], sf[f][bb+1]);
      uint32_t g0B = pkbf(sf[f][bb+2], sf[f][bb+3]);
      uint32_t g1A = pkbf(sf[f][bb+4], sf[f][bb+5]);
      uint32_t g1B = pkbf(sf[f][bb+6], sf[f][bb+7]);
      uint32_t ownA = h ? g1A : g0A, ownB = h ? g1B : g0B;
      uint32_t sndA = h ? g0A : g1A, sndB = h ? g0B : g1B;
      uint32_t rcvA = __shfl_xor(sndA, 32, 64);
      uint32_t rcvB = __shfl_xor(sndB, 32, 64);
      union { uint32_t u[4]; bf16x8 v; } pf;
      if (h == 0) { pf.u[0]=ownA; pf.u[1]=ownB; pf.u[2]=rcvA; pf.u[3]=rcvB; }
      else        { pf.u[0]=rcvA; pf.u[1]=rcvB; pf.u[2]=ownA; pf.u[3]=ownB; }
      #pragma unroll
      for (int mf=0;mf<2;mf++) {
        int row = mf*32 + q;
        int byte = (row*128 + 32*s + 16*h) ^ ((row&7)<<4);
        bf16x8 vf = *(const bf16x8*)((const char*)&Vt[cur][0] + byte);
        ot[mf] = __builtin_amdgcn_mfma_f32_32x32x16_bf16(vf, pf.v, ot[mf], 0,0,0);
      }
    }

    if (pre) writeVt(na, nb, cur^1);   // vmcnt wait inserted here, after compute
    __syncthreads();                   // drains K gload_lds for next tile
  }

  // normalize + store O[token][head*64+d]
  float inv = 1.0f / lrun;
  int b = bh >> 4, head = bh & 15;
  size_t orow = ((size_t)b*SEQ + q0 + q)*HIDDEN + head*HD;
  #pragma unroll
  for (int mf=0;mf<2;mf++)
    #pragma unroll
    for (int r=0;r<16;r++) {
      int dd = mf*32 + (r&3) + 8*(r>>2) + 4*h;
      Og[orow + dd] = (bf16)(ot[mf][r]*inv);
    }
}

extern "C" void kernel_launch(void* const* d_in, const int* in_sizes, int n_in,
                              void* d_out, int out_size, void* d_ws, size_t ws_size,
                              hipStream_t stream)
{
  (void)in_sizes; (void)n_in; (void)out_size; (void)ws_size;
  const float* x    = (const float*)d_in[0];
  const float* wqkv = (const float*)d_in[1];
  const float* wout = (const float*)d_in[2];
  float* out = (float*)d_out;
  char* ws = (char*)d_ws;
  bf16* xb    = (bf16*)(ws);                 //  8 MiB  [4096][1024]
  bf16* wqkvb = (bf16*)(ws + 8388608);       //  6 MiB  [3072][1024]
  bf16* woutb = (bf16*)(ws + 14680064);      //  2 MiB  [1024][1024]
  bf16* Q     = (bf16*)(ws + 16777216);      //  8 MiB  [2][16][2048][64] (pre-scaled QSCALE)
  bf16* K     = (bf16*)(ws + 25165824);      //  8 MiB
  bf16* V     = (bf16*)(ws + 33554432);      //  8 MiB
  bf16* O     = (bf16*)(ws + 41943040);      //  8 MiB  [4096][1024]

  k_convert<<<8192, 256, 0, stream>>>(x, wqkv, wout, xb, wqkvb, woutb);
  k_gemm<0,128><<<32*24, 256, 0, stream>>>(xb, wqkvb, Q, K, V, nullptr, NTOK, E3, HIDDEN, 24);
  k_attn<<<512, 256, 0, stream>>>(Q, K, V, O);
  k_gemm<1,64><<<64*8, 256, 0, stream>>>(O, woutb, nullptr, nullptr, nullptr, out, NTOK, HIDDEN, HIDDEN, 8);
}

// Round 3
// 204.295 us; speedup vs baseline: 1.1244x; 1.1244x over previous
//
#include <hip/hip_runtime.h>
#include <hip/hip_bf16.h>
#include <stdint.h>

typedef __bf16 bf16;
typedef __bf16 bf16x8 __attribute__((ext_vector_type(8)));
typedef float f32x4 __attribute__((ext_vector_type(4)));

#define HIDDEN 1024
#define HEADS  16
#define HD     64
#define SEQ    2048
#define BATCH  2
#define NTOK   (BATCH*SEQ)
#define E3     (3*HIDDEN)

// softmax scale 1/8 with log2(e) folded in, applied to Q at QKV-GEMM epilogue
#define QSCALE (0.125f * 1.44269504088896f)

#if __has_builtin(__builtin_amdgcn_exp2f)
#define EXP2(x) __builtin_amdgcn_exp2f(x)
#else
#define EXP2(x) __expf((x) * 0.69314718055995f)
#endif

static __device__ __forceinline__ uint32_t pkbf(float a, float b) {
  union { bf16 h[2]; uint32_t u; } x;
  x.h[0] = (bf16)a; x.h[1] = (bf16)b;
  return x.u;
}

// ---------------- f32 -> bf16 convert of x, w_qkv, w_out ----------------
__global__ __launch_bounds__(256) void k_convert(
    const float* __restrict__ x, const float* __restrict__ wqkv, const float* __restrict__ wout,
    bf16* __restrict__ xb, bf16* __restrict__ wqkvb, bf16* __restrict__ woutb)
{
  const int NX = NTOK*HIDDEN/4, NW = E3*HIDDEN/4;
  int i = blockIdx.x*256 + threadIdx.x;
  const float4* s; bf16* d; int o;
  if (i < NX)            { s=(const float4*)x;    d=xb;    o=i; }
  else if (i < NX+NW)    { s=(const float4*)wqkv; d=wqkvb; o=i-NX; }
  else                   { s=(const float4*)wout; d=woutb; o=i-NX-NW; }
  float4 v = s[o];
  union { bf16 b[4]; uint2 u; } p;
  p.b[0]=(bf16)v.x; p.b[1]=(bf16)v.y; p.b[2]=(bf16)v.z; p.b[3]=(bf16)v.w;
  *(uint2*)(d + (size_t)o*4) = p.u;
}

// ---------------- bf16 GEMM  C[M,N] = A[M,K] * B[N,K]^T ----------------
// EPI=0: scatter to Q/K/V head layout (Q scaled by QSCALE).  EPI=1: f32 out.
template<int EPI, int BM>
__global__ __launch_bounds__(256) void k_gemm(
    const bf16* __restrict__ A, const bf16* __restrict__ B,
    bf16* __restrict__ Oq, bf16* __restrict__ Ok, bf16* __restrict__ Ov,
    float* __restrict__ Of, int M, int N, int K, int nbn)
{
  constexpr int MI = BM/32;
  __shared__ bf16 As[BM*32];
  __shared__ bf16 Bs[128*32];
  const int t = threadIdx.x;
  const int lane = t & 63;
  const int w = t >> 6;
  const int g = lane >> 4;
  const int l15 = lane & 15;
  const int wm = (w >> 1) * (BM/2), wn = (w & 1) * 64;
  const int bm = blockIdx.x / nbn, bn = blockIdx.x % nbn;
  const int brow = bm*BM, bcol = bn*128;

  f32x4 acc[MI][4];
  #pragma unroll
  for (int mi=0;mi<MI;mi++)
    #pragma unroll
    for (int ni=0;ni<4;ni++)
      #pragma unroll
      for (int r=0;r<4;r++) acc[mi][ni][r] = 0.f;

  const int nk = K >> 5;
  for (int kt = 0; kt < nk; ++kt) {
    if constexpr (BM == 128) {
      int ch = w*128 + lane;
      const bf16* ga = A + (size_t)(brow + (ch>>2))*K + kt*32 + (ch&3)*8;
      __builtin_amdgcn_global_load_lds((const uint32_t*)ga, (uint32_t*)(As + (w*128)*8), 16, 0, 0);
      int ch2 = ch + 64;
      const bf16* ga2 = A + (size_t)(brow + (ch2>>2))*K + kt*32 + (ch2&3)*8;
      __builtin_amdgcn_global_load_lds((const uint32_t*)ga2, (uint32_t*)(As + (w*128+64)*8), 16, 0, 0);
    } else {
      int ch = w*64 + lane;
      const bf16* ga = A + (size_t)(brow + (ch>>2))*K + kt*32 + (ch&3)*8;
      __builtin_amdgcn_global_load_lds((const uint32_t*)ga, (uint32_t*)(As + (w*64)*8), 16, 0, 0);
    }
    {
      int ch = w*128 + lane;
      const bf16* gb = B + (size_t)(bcol + (ch>>2))*K + kt*32 + (ch&3)*8;
      __builtin_amdgcn_global_load_lds((const uint32_t*)gb, (uint32_t*)(Bs + (w*128)*8), 16, 0, 0);
      int ch2 = ch + 64;
      const bf16* gb2 = B + (size_t)(bcol + (ch2>>2))*K + kt*32 + (ch2&3)*8;
      __builtin_amdgcn_global_load_lds((const uint32_t*)gb2, (uint32_t*)(Bs + (w*128+64)*8), 16, 0, 0);
    }
    __syncthreads();
    bf16x8 af[MI], bfr[4];
    #pragma unroll
    for (int mi=0;mi<MI;mi++) af[mi]  = *(const bf16x8*)(As + (wm + mi*16 + l15)*32 + g*8);
    #pragma unroll
    for (int ni=0;ni<4;ni++) bfr[ni] = *(const bf16x8*)(Bs + (wn + ni*16 + l15)*32 + g*8);
    #pragma unroll
    for (int mi=0;mi<MI;mi++)
      #pragma unroll
      for (int ni=0;ni<4;ni++)
        acc[mi][ni] = __builtin_amdgcn_mfma_f32_16x16x32_bf16(af[mi], bfr[ni], acc[mi][ni], 0, 0, 0);
    __syncthreads();
  }

  #pragma unroll
  for (int mi=0;mi<MI;mi++) {
    #pragma unroll
    for (int ni=0;ni<4;ni++) {
      #pragma unroll
      for (int r=0;r<4;r++) {
        float val = acc[mi][ni][r];
        int m = brow + wm + mi*16 + 4*g + r;
        int e = bcol + wn + ni*16 + l15;
        if (EPI == 0) {
          int part = e >> 10, we = e & 1023;
          int hh = we >> 6, dd = we & 63;
          int b = m >> 11, sb = m & 2047;
          size_t idx = (((size_t)b*HEADS + hh)*SEQ + sb)*HD + dd;
          if (part == 0)      Oq[idx] = (bf16)(val * QSCALE);
          else if (part == 1) Ok[idx] = (bf16)val;
          else                Ov[idx] = (bf16)val;
        } else {
          Of[(size_t)m*HIDDEN + e] = val;
        }
      }
    }
  }
}

// ---------------- flash attention, 16 q-rows per wave, 16x16x32 MFMA ----------------
// grid: 32 bh * 32 qblocks (64 rows each); block: 4 waves, wave owns 16 q rows.
// Swapped QK^T (scores^T, q = lane&15).  kv k-slot permutation chosen so the PV
// B-fragment is lane-local (zero shuffles); permutation absorbed into V staging.
__global__ __launch_bounds__(256, 4) void k_attn(
    const bf16* __restrict__ Qg, const bf16* __restrict__ Kg, const bf16* __restrict__ Vg,
    bf16* __restrict__ Og)
{
  __shared__ bf16 Kl[64*64];   // [kv][d] 128B rows, 16B-chunk XOR swizzle by (row&7)
  __shared__ bf16 Vt[64*64];   // [d][pos] 128B rows, pos = kv-permuted, same swizzle
  const int t = threadIdx.x;
  const int lane = t & 63;
  const int w = t >> 6;
  const int g = lane >> 4;      // 0..3
  const int q = lane & 15;      // this lane's q row
  const int bh = blockIdx.x >> 5;
  const int qb = blockIdx.x & 31;
  const int q0 = qb*64 + w*16;
  const size_t bhS = (size_t)bh * SEQ * HD;

  // Q fragments (B-operand): k-slot 8g+j of chunk kc -> d = 32kc + 8g + j
  bf16x8 qf[2];
  {
    const bf16* qrow = Qg + bhS + (size_t)(q0 + q)*HD + 8*g;
    qf[0] = *(const bf16x8*)(qrow);
    qf[1] = *(const bf16x8*)(qrow + 32);
  }

  f32x4 ot[4];                 // O^T[d = 16df+4g+r][q]
  #pragma unroll
  for (int df=0;df<4;df++)
    #pragma unroll
    for (int r=0;r<4;r++) ot[df][r] = 0.f;
  float mrun = -3.0e38f, lrun = 0.f;

  // V staging: thread handles kv pair (kv0,kv0+1) x 8 d's; permuted column pos0
  const int kv0 = (t & 31)*2;
  const int dd0 = (t >> 5)*8;
  const int kvf0 = kv0 >> 4, gv = (kv0 >> 2) & 3, rv = kv0 & 3;
  const int pos0 = 32*(kvf0 >> 1) + 8*gv + 4*(kvf0 & 1) + rv;   // even

  for (int it = 0; it < SEQ/64; ++it) {
    __syncthreads();
    { // K tile via global_load_lds, linear LDS dest, pre-swizzled global source
      int ch = w*128 + lane;
      int row = ch>>3, o16 = ch&7;
      const bf16* gp = Kg + bhS + (size_t)(it*64+row)*HD + ((o16*8) ^ ((row&7)*8));
      __builtin_amdgcn_global_load_lds((const uint32_t*)gp, (uint32_t*)(Kl + (w*128)*8), 16, 0, 0);
      int ch2 = ch + 64;
      int row2 = ch2>>3, o16b = ch2&7;
      const bf16* gp2 = Kg + bhS + (size_t)(it*64+row2)*HD + ((o16b*8) ^ ((row2&7)*8));
      __builtin_amdgcn_global_load_lds((const uint32_t*)gp2, (uint32_t*)(Kl + (w*128+64)*8), 16, 0, 0);
    }
    { // V tile -> Vt[d][pos] via v_perm transpose, swizzled ds_write
      const bf16* vg = Vg + bhS + (size_t)(it*64 + kv0)*HD + dd0;
      uint4 va = *(const uint4*)vg;
      uint4 vb = *(const uint4*)(vg + HD);
      const uint32_t* pa = (const uint32_t*)&va;
      const uint32_t* pb = (const uint32_t*)&vb;
      #pragma unroll
      for (int jj=0;jj<8;jj++) {
        int dd = dd0 + jj;                       // dd&7 == jj
        uint32_t pr = __builtin_amdgcn_perm(pb[jj>>1], pa[jj>>1],
                                            (jj&1) ? 0x07060302u : 0x05040100u);
        int byte = (dd*128 + pos0*2) ^ (jj<<4);
        *(uint32_t*)((char*)Vt + byte) = pr;
      }
    }
    __syncthreads();

    // QK^T swapped: sf[kvf] = scores^T fragment; lane holds kv = 16kvf+4g+r, col q
    f32x4 sf[4];
    #pragma unroll
    for (int kvf=0;kvf<4;kvf++)
      #pragma unroll
      for (int r=0;r<4;r++) sf[kvf][r] = 0.f;
    #pragma unroll
    for (int kvf=0;kvf<4;kvf++) {
      int row = 16*kvf + q;
      #pragma unroll
      for (int kc=0;kc<2;kc++) {
        int byte = row*128 + (((16*g + 64*kc)) ^ ((row&7)<<4));
        bf16x8 kf = *(const bf16x8*)((const char*)Kl + byte);
        sf[kvf] = __builtin_amdgcn_mfma_f32_16x16x32_bf16(kf, qf[kc], sf[kvf], 0,0,0);
      }
    }

    // online softmax (log2 domain, Q pre-scaled); row q reduce across 4-lane g-group
    float pm = -3.0e38f;
    #pragma unroll
    for (int kvf=0;kvf<4;kvf++)
      #pragma unroll
      for (int r=0;r<4;r++) pm = fmaxf(pm, sf[kvf][r]);
    pm = fmaxf(pm, __shfl_xor(pm, 16, 64));
    pm = fmaxf(pm, __shfl_xor(pm, 32, 64));

    if (__any(pm - mrun > 8.f)) {               // defer-max: rescale only on growth
      float mnew = fmaxf(mrun, pm);
      float alpha = EXP2(mrun - mnew);
      lrun *= alpha;
      #pragma unroll
      for (int df=0;df<4;df++)
        #pragma unroll
        for (int r=0;r<4;r++) ot[df][r] *= alpha;
      mrun = mnew;
    }
    float rs = 0.f;
    #pragma unroll
    for (int kvf=0;kvf<4;kvf++)
      #pragma unroll
      for (int r=0;r<4;r++) { float p = EXP2(sf[kvf][r]-mrun); sf[kvf][r]=p; rs += p; }
    rs += __shfl_xor(rs, 16, 64);
    rs += __shfl_xor(rs, 32, 64);
    lrun += rs;

    // pack P (lane-local B-fragments thanks to kv-slot permutation)
    uint32_t pk[4][2];
    #pragma unroll
    for (int kvf=0;kvf<4;kvf++) {
      pk[kvf][0] = pkbf(sf[kvf][0], sf[kvf][1]);
      pk[kvf][1] = pkbf(sf[kvf][2], sf[kvf][3]);
    }

    // PV: O^T += V^T * P^T
    #pragma unroll
    for (int kc=0;kc<2;kc++) {
      union { uint32_t u[4]; bf16x8 v; } pf;
      pf.u[0] = pk[2*kc][0]; pf.u[1] = pk[2*kc][1];
      pf.u[2] = pk[2*kc+1][0]; pf.u[3] = pk[2*kc+1][1];
      #pragma unroll
      for (int df=0;df<4;df++) {
        int row = 16*df + q;
        int byte = row*128 + (((16*g + 64*kc)) ^ ((row&7)<<4));
        bf16x8 vf = *(const bf16x8*)((const char*)Vt + byte);
        ot[df] = __builtin_amdgcn_mfma_f32_16x16x32_bf16(vf, pf.v, ot[df], 0,0,0);
      }
    }
  }

  // normalize + store O[token][head*64 + d], 8B per df
  float inv = 1.0f / lrun;
  int b = bh >> 4, head = bh & 15;
  size_t orow = ((size_t)b*SEQ + q0 + q)*HIDDEN + head*HD;
  #pragma unroll
  for (int df=0;df<4;df++) {
    uint2 pr;
    pr.x = pkbf(ot[df][0]*inv, ot[df][1]*inv);
    pr.y = pkbf(ot[df][2]*inv, ot[df][3]*inv);
    *(uint2*)(Og + orow + 16*df + 4*g) = pr;
  }
}

extern "C" void kernel_launch(void* const* d_in, const int* in_sizes, int n_in,
                              void* d_out, int out_size, void* d_ws, size_t ws_size,
                              hipStream_t stream)
{
  (void)in_sizes; (void)n_in; (void)out_size; (void)ws_size;
  const float* x    = (const float*)d_in[0];
  const float* wqkv = (const float*)d_in[1];
  const float* wout = (const float*)d_in[2];
  float* out = (float*)d_out;
  char* ws = (char*)d_ws;
  bf16* xb    = (bf16*)(ws);                 //  8 MiB  [4096][1024]
  bf16* wqkvb = (bf16*)(ws + 8388608);       //  6 MiB  [3072][1024]
  bf16* woutb = (bf16*)(ws + 14680064);      //  2 MiB  [1024][1024]
  bf16* Q     = (bf16*)(ws + 16777216);      //  8 MiB  [2][16][2048][64] (pre-scaled QSCALE)
  bf16* K     = (bf16*)(ws + 25165824);      //  8 MiB
  bf16* V     = (bf16*)(ws + 33554432);      //  8 MiB
  bf16* O     = (bf16*)(ws + 41943040);      //  8 MiB  [4096][1024]

  k_convert<<<8192, 256, 0, stream>>>(x, wqkv, wout, xb, wqkvb, woutb);
  k_gemm<0,128><<<32*24, 256, 0, stream>>>(xb, wqkvb, Q, K, V, nullptr, NTOK, E3, HIDDEN, 24);
  k_attn<<<1024, 256, 0, stream>>>(Q, K, V, O);
  k_gemm<1,64><<<64*8, 256, 0, stream>>>(O, woutb, nullptr, nullptr, nullptr, out, NTOK, HIDDEN, HIDDEN, 8);
}

// Round 5
// 194.908 us; speedup vs baseline: 1.1785x; 1.0482x over previous
//
#include <hip/hip_runtime.h>
#include <hip/hip_bf16.h>
#include <stdint.h>

typedef __bf16 bf16;
typedef __bf16 bf16x8 __attribute__((ext_vector_type(8)));
typedef float f32x4 __attribute__((ext_vector_type(4)));

#define HIDDEN 1024
#define HEADS  16
#define HD     64
#define SEQ    2048
#define BATCH  2
#define NTOK   (BATCH*SEQ)
#define E3     (3*HIDDEN)

// softmax scale 1/8 with log2(e) folded in, applied to Q at QKV-GEMM epilogue
#define QSCALE (0.125f * 1.44269504088896f)

#if __has_builtin(__builtin_amdgcn_exp2f)
#define EXP2(x) __builtin_amdgcn_exp2f(x)
#else
#define EXP2(x) __expf((x) * 0.69314718055995f)
#endif

static __device__ __forceinline__ uint32_t pkbf(float a, float b) {
  union { bf16 h[2]; uint32_t u; } x;
  x.h[0] = (bf16)a; x.h[1] = (bf16)b;
  return x.u;
}

// ---------------- f32 -> bf16 convert of x, w_qkv, w_out ----------------
__global__ __launch_bounds__(256) void k_convert(
    const float* __restrict__ x, const float* __restrict__ wqkv, const float* __restrict__ wout,
    bf16* __restrict__ xb, bf16* __restrict__ wqkvb, bf16* __restrict__ woutb)
{
  const int NX = NTOK*HIDDEN/4, NW = E3*HIDDEN/4;
  int i = blockIdx.x*256 + threadIdx.x;
  const float4* s; bf16* d; int o;
  if (i < NX)            { s=(const float4*)x;    d=xb;    o=i; }
  else if (i < NX+NW)    { s=(const float4*)wqkv; d=wqkvb; o=i-NX; }
  else                   { s=(const float4*)wout; d=woutb; o=i-NX-NW; }
  float4 v = s[o];
  union { bf16 b[4]; uint2 u; } p;
  p.b[0]=(bf16)v.x; p.b[1]=(bf16)v.y; p.b[2]=(bf16)v.z; p.b[3]=(bf16)v.w;
  *(uint2*)(d + (size_t)o*4) = p.u;
}

// ---------------- bf16 GEMM  C[M,N] = A[M,K] * B[N,K]^T ----------------
// EPI=0: scatter to Q/K/V head layout (Q scaled by QSCALE).  EPI=1: f32 out.
template<int EPI, int BM>
__global__ __launch_bounds__(256) void k_gemm(
    const bf16* __restrict__ A, const bf16* __restrict__ B,
    bf16* __restrict__ Oq, bf16* __restrict__ Ok, bf16* __restrict__ Ov,
    float* __restrict__ Of, int M, int N, int K, int nbn)
{
  constexpr int MI = BM/32;
  __shared__ bf16 As[BM*32];
  __shared__ bf16 Bs[128*32];
  const int t = threadIdx.x;
  const int lane = t & 63;
  const int w = t >> 6;
  const int g = lane >> 4;
  const int l15 = lane & 15;
  const int wm = (w >> 1) * (BM/2), wn = (w & 1) * 64;
  const int bm = blockIdx.x / nbn, bn = blockIdx.x % nbn;
  const int brow = bm*BM, bcol = bn*128;

  f32x4 acc[MI][4];
  #pragma unroll
  for (int mi=0;mi<MI;mi++)
    #pragma unroll
    for (int ni=0;ni<4;ni++)
      #pragma unroll
      for (int r=0;r<4;r++) acc[mi][ni][r] = 0.f;

  const int nk = K >> 5;
  for (int kt = 0; kt < nk; ++kt) {
    if constexpr (BM == 128) {
      int ch = w*128 + lane;
      const bf16* ga = A + (size_t)(brow + (ch>>2))*K + kt*32 + (ch&3)*8;
      __builtin_amdgcn_global_load_lds((const uint32_t*)ga, (uint32_t*)(As + (w*128)*8), 16, 0, 0);
      int ch2 = ch + 64;
      const bf16* ga2 = A + (size_t)(brow + (ch2>>2))*K + kt*32 + (ch2&3)*8;
      __builtin_amdgcn_global_load_lds((const uint32_t*)ga2, (uint32_t*)(As + (w*128+64)*8), 16, 0, 0);
    } else {
      int ch = w*64 + lane;
      const bf16* ga = A + (size_t)(brow + (ch>>2))*K + kt*32 + (ch&3)*8;
      __builtin_amdgcn_global_load_lds((const uint32_t*)ga, (uint32_t*)(As + (w*64)*8), 16, 0, 0);
    }
    {
      int ch = w*128 + lane;
      const bf16* gb = B + (size_t)(bcol + (ch>>2))*K + kt*32 + (ch&3)*8;
      __builtin_amdgcn_global_load_lds((const uint32_t*)gb, (uint32_t*)(Bs + (w*128)*8), 16, 0, 0);
      int ch2 = ch + 64;
      const bf16* gb2 = B + (size_t)(bcol + (ch2>>2))*K + kt*32 + (ch2&3)*8;
      __builtin_amdgcn_global_load_lds((const uint32_t*)gb2, (uint32_t*)(Bs + (w*128+64)*8), 16, 0, 0);
    }
    __syncthreads();
    bf16x8 af[MI], bfr[4];
    #pragma unroll
    for (int mi=0;mi<MI;mi++) af[mi]  = *(const bf16x8*)(As + (wm + mi*16 + l15)*32 + g*8);
    #pragma unroll
    for (int ni=0;ni<4;ni++) bfr[ni] = *(const bf16x8*)(Bs + (wn + ni*16 + l15)*32 + g*8);
    #pragma unroll
    for (int mi=0;mi<MI;mi++)
      #pragma unroll
      for (int ni=0;ni<4;ni++)
        acc[mi][ni] = __builtin_amdgcn_mfma_f32_16x16x32_bf16(af[mi], bfr[ni], acc[mi][ni], 0, 0, 0);
    __syncthreads();
  }

  #pragma unroll
  for (int mi=0;mi<MI;mi++) {
    #pragma unroll
    for (int ni=0;ni<4;ni++) {
      #pragma unroll
      for (int r=0;r<4;r++) {
        float val = acc[mi][ni][r];
        int m = brow + wm + mi*16 + 4*g + r;
        int e = bcol + wn + ni*16 + l15;
        if (EPI == 0) {
          int part = e >> 10, we = e & 1023;
          int hh = we >> 6, dd = we & 63;
          int b = m >> 11, sb = m & 2047;
          size_t idx = (((size_t)b*HEADS + hh)*SEQ + sb)*HD + dd;
          if (part == 0)      Oq[idx] = (bf16)(val * QSCALE);
          else if (part == 1) Ok[idx] = (bf16)val;
          else                Ov[idx] = (bf16)val;
        } else {
          Of[(size_t)m*HIDDEN + e] = val;
        }
      }
    }
  }
}

// ---------------- flash attention, 32 q-rows per wave, 16x16x32 MFMA ----------------
// grid: 32 bh * 16 qblocks (128 rows each); block: 4 waves, wave owns 32 q rows
// (two 16-row q-sets sharing each K/V LDS fragment read -> LDS reads per q-row halved).
// Reg-staged K/V with early issue: global->reg loads for tile i+1 issued right after
// the post-stage barrier of tile i, ds_written at the next top barrier (T14).
__global__ __launch_bounds__(256, 2) void k_attn(
    const bf16* __restrict__ Qg, const bf16* __restrict__ Kg, const bf16* __restrict__ Vg,
    bf16* __restrict__ Og)
{
  __shared__ bf16 Kl[64*64];   // [kv][d] 128B rows, 16B-chunk XOR swizzle by (row&7)
  __shared__ bf16 Vt[64*64];   // [d][pos] 128B rows, pos = kv-permuted, same swizzle
  const int t = threadIdx.x;
  const int lane = t & 63;
  const int w = t >> 6;
  const int g = lane >> 4;      // 0..3
  const int q = lane & 15;      // this lane's q row (within 16-row q-set)
  const int bh = blockIdx.x >> 4;
  const int qb = blockIdx.x & 15;
  const int q0 = qb*128 + w*32;
  const size_t bhS = (size_t)bh * SEQ * HD;

  // Q fragments (B-operand): k-slot 8g+j of chunk kc -> d = 32kc + 8g + j
  bf16x8 qf[2][2];
  #pragma unroll
  for (int qs=0;qs<2;qs++) {
    const bf16* qrow = Qg + bhS + (size_t)(q0 + 16*qs + q)*HD + 8*g;
    qf[qs][0] = *(const bf16x8*)(qrow);
    qf[qs][1] = *(const bf16x8*)(qrow + 32);
  }

  f32x4 ot[2][4];              // O^T[d = 16df+4g+r][q], per q-set
  #pragma unroll
  for (int qs=0;qs<2;qs++)
    #pragma unroll
    for (int df=0;df<4;df++)
      #pragma unroll
      for (int r=0;r<4;r++) ot[qs][df][r] = 0.f;
  float mrun0 = -3.0e38f, mrun1 = -3.0e38f, lrun0 = 0.f, lrun1 = 0.f;

  // K staging: thread t handles 16B chunks (row=t>>3, part=t&7) and (+32 rows)
  const int kr0 = t >> 3, kp0 = t & 7;
  // V staging: thread handles kv pair (kv0,kv0+1) x 8 d's; permuted column pos0
  const int kv0 = (t & 31)*2;
  const int dd0 = (t >> 5)*8;
  const int kvf0 = kv0 >> 4, gv = (kv0 >> 2) & 3, rv = kv0 & 3;
  const int pos0 = 32*(kvf0 >> 1) + 8*gv + 4*(kvf0 & 1) + rv;   // even

  auto loadK = [&](int it, uint4& a, uint4& b) {
    const bf16* p0 = Kg + bhS + (size_t)(it*64 + kr0)*HD + kp0*8;
    a = *(const uint4*)p0;
    b = *(const uint4*)(p0 + 32*HD);
  };
  auto writeK = [&](uint4 a, uint4 b) {
    int sw = (kp0 ^ (kr0 & 7)) * 16;          // (kr0+32)&7 == kr0&7
    *(uint4*)((char*)Kl + kr0*128 + sw) = a;
    *(uint4*)((char*)Kl + (kr0+32)*128 + sw) = b;
  };
  auto loadV = [&](int it, uint4& a, uint4& b) {
    const bf16* vg = Vg + bhS + (size_t)(it*64 + kv0)*HD + dd0;
    a = *(const uint4*)vg;
    b = *(const uint4*)(vg + HD);
  };
  auto writeVt = [&](uint4 va, uint4 vb) {
    const uint32_t* pa = (const uint32_t*)&va;
    const uint32_t* pb = (const uint32_t*)&vb;
    #pragma unroll
    for (int jj=0;jj<8;jj++) {
      int dd = dd0 + jj;                       // dd&7 == jj
      uint32_t pr = __builtin_amdgcn_perm(pb[jj>>1], pa[jj>>1],
                                          (jj&1) ? 0x07060302u : 0x05040100u);
      int byte = (dd*128 + pos0*2) ^ (jj<<4);
      *(uint32_t*)((char*)Vt + byte) = pr;
    }
  };

  uint4 ka, kb, va, vb;
  loadK(0, ka, kb);
  loadV(0, va, vb);

  const int NT = SEQ/64;
  for (int it = 0; it < NT; ++it) {
    __syncthreads();             // previous tile's LDS reads complete
    writeK(ka, kb);
    writeVt(va, vb);
    __syncthreads();             // tile staged
    if (it+1 < NT) {             // early-issue next tile's global loads
      loadK(it+1, ka, kb);
      loadV(it+1, va, vb);
    }

    // QK^T swapped: sf[qs][kvf]; lane holds kv = 16kvf+4g+r, col q (of q-set qs)
    f32x4 sf[2][4];
    #pragma unroll
    for (int qs=0;qs<2;qs++)
      #pragma unroll
      for (int kvf=0;kvf<4;kvf++)
        #pragma unroll
        for (int r=0;r<4;r++) sf[qs][kvf][r] = 0.f;
    #pragma unroll
    for (int kvf=0;kvf<4;kvf++) {
      int row = 16*kvf + q;
      #pragma unroll
      for (int kc=0;kc<2;kc++) {
        int byte = row*128 + ((16*g + 64*kc) ^ ((row&7)<<4));
        bf16x8 kf = *(const bf16x8*)((const char*)Kl + byte);
        sf[0][kvf] = __builtin_amdgcn_mfma_f32_16x16x32_bf16(kf, qf[0][kc], sf[0][kvf], 0,0,0);
        sf[1][kvf] = __builtin_amdgcn_mfma_f32_16x16x32_bf16(kf, qf[1][kc], sf[1][kvf], 0,0,0);
      }
    }

    // online softmax (log2 domain), two independent row-states per lane
    float pm0 = -3.0e38f, pm1 = -3.0e38f;
    #pragma unroll
    for (int kvf=0;kvf<4;kvf++)
      #pragma unroll
      for (int r=0;r<4;r++) {
        pm0 = fmaxf(pm0, sf[0][kvf][r]);
        pm1 = fmaxf(pm1, sf[1][kvf][r]);
      }
    pm0 = fmaxf(pm0, __shfl_xor(pm0, 16, 64));
    pm0 = fmaxf(pm0, __shfl_xor(pm0, 32, 64));
    pm1 = fmaxf(pm1, __shfl_xor(pm1, 16, 64));
    pm1 = fmaxf(pm1, __shfl_xor(pm1, 32, 64));

    bool need = (pm0 - mrun0 > 8.f) || (pm1 - mrun1 > 8.f);
    if (__any(need)) {           // defer-max: rescale only on significant growth
      float mn0 = fmaxf(mrun0, pm0), mn1 = fmaxf(mrun1, pm1);
      float a0 = EXP2(mrun0 - mn0), a1 = EXP2(mrun1 - mn1);
      lrun0 *= a0; lrun1 *= a1;
      #pragma unroll
      for (int df=0;df<4;df++)
        #pragma unroll
        for (int r=0;r<4;r++) { ot[0][df][r] *= a0; ot[1][df][r] *= a1; }
      mrun0 = mn0; mrun1 = mn1;
    }
    float rs0 = 0.f, rs1 = 0.f;
    #pragma unroll
    for (int kvf=0;kvf<4;kvf++)
      #pragma unroll
      for (int r=0;r<4;r++) {
        float p0 = EXP2(sf[0][kvf][r] - mrun0); sf[0][kvf][r] = p0; rs0 += p0;
        float p1 = EXP2(sf[1][kvf][r] - mrun1); sf[1][kvf][r] = p1; rs1 += p1;
      }
    rs0 += __shfl_xor(rs0, 16, 64); rs0 += __shfl_xor(rs0, 32, 64);
    rs1 += __shfl_xor(rs1, 16, 64); rs1 += __shfl_xor(rs1, 32, 64);
    lrun0 += rs0; lrun1 += rs1;

    // pack P (lane-local B-fragments thanks to kv-slot permutation)
    uint32_t pk[2][4][2];
    #pragma unroll
    for (int qs=0;qs<2;qs++)
      #pragma unroll
      for (int kvf=0;kvf<4;kvf++) {
        pk[qs][kvf][0] = pkbf(sf[qs][kvf][0], sf[qs][kvf][1]);
        pk[qs][kvf][1] = pkbf(sf[qs][kvf][2], sf[qs][kvf][3]);
      }

    // PV: O^T += V^T * P^T; each vf read feeds both q-sets
    #pragma unroll
    for (int kc=0;kc<2;kc++) {
      union { uint32_t u[4]; bf16x8 v; } pf0, pf1;
      pf0.u[0] = pk[0][2*kc][0]; pf0.u[1] = pk[0][2*kc][1];
      pf0.u[2] = pk[0][2*kc+1][0]; pf0.u[3] = pk[0][2*kc+1][1];
      pf1.u[0] = pk[1][2*kc][0]; pf1.u[1] = pk[1][2*kc][1];
      pf1.u[2] = pk[1][2*kc+1][0]; pf1.u[3] = pk[1][2*kc+1][1];
      #pragma unroll
      for (int df=0;df<4;df++) {
        int row = 16*df + q;
        int byte = row*128 + ((16*g + 64*kc) ^ ((row&7)<<4));
        bf16x8 vf = *(const bf16x8*)((const char*)Vt + byte);
        ot[0][df] = __builtin_amdgcn_mfma_f32_16x16x32_bf16(vf, pf0.v, ot[0][df], 0,0,0);
        ot[1][df] = __builtin_amdgcn_mfma_f32_16x16x32_bf16(vf, pf1.v, ot[1][df], 0,0,0);
      }
    }
  }

  // normalize + store O[token][head*64 + d], 8B per (qs,df)
  float inv0 = 1.0f / lrun0, inv1 = 1.0f / lrun1;
  int b = bh >> 4, head = bh & 15;
  #pragma unroll
  for (int qs=0;qs<2;qs++) {
    float inv = qs ? inv1 : inv0;
    size_t orow = ((size_t)b*SEQ + q0 + 16*qs + q)*HIDDEN + head*HD;
    #pragma unroll
    for (int df=0;df<4;df++) {
      uint2 pr;
      pr.x = pkbf(ot[qs][df][0]*inv, ot[qs][df][1]*inv);
      pr.y = pkbf(ot[qs][df][2]*inv, ot[qs][df][3]*inv);
      *(uint2*)(Og + orow + 16*df + 4*g) = pr;
    }
  }
}

extern "C" void kernel_launch(void* const* d_in, const int* in_sizes, int n_in,
                              void* d_out, int out_size, void* d_ws, size_t ws_size,
                              hipStream_t stream)
{
  (void)in_sizes; (void)n_in; (void)out_size; (void)ws_size;
  const float* x    = (const float*)d_in[0];
  const float* wqkv = (const float*)d_in[1];
  const float* wout = (const float*)d_in[2];
  float* out = (float*)d_out;
  char* ws = (char*)d_ws;
  bf16* xb    = (bf16*)(ws);                 //  8 MiB  [4096][1024]
  bf16* wqkvb = (bf16*)(ws + 8388608);       //  6 MiB  [3072][1024]
  bf16* woutb = (bf16*)(ws + 14680064);      //  2 MiB  [1024][1024]
  bf16* Q     = (bf16*)(ws + 16777216);      //  8 MiB  [2][16][2048][64] (pre-scaled QSCALE)
  bf16* K     = (bf16*)(ws + 25165824);      //  8 MiB
  bf16* V     = (bf16*)(ws + 33554432);      //  8 MiB
  bf16* O     = (bf16*)(ws + 41943040);      //  8 MiB  [4096][1024]

  k_convert<<<8192, 256, 0, stream>>>(x, wqkv, wout, xb, wqkvb, woutb);
  k_gemm<0,128><<<32*24, 256, 0, stream>>>(xb, wqkvb, Q, K, V, nullptr, NTOK, E3, HIDDEN, 24);
  k_attn<<<512, 256, 0, stream>>>(Q, K, V, O);
  k_gemm<1,64><<<64*8, 256, 0, stream>>>(O, woutb, nullptr, nullptr, nullptr, out, NTOK, HIDDEN, HIDDEN, 8);
}

// Round 6
// 180.270 us; speedup vs baseline: 1.2742x; 1.0812x over previous
//
#include <hip/hip_runtime.h>
#include <hip/hip_bf16.h>
#include <stdint.h>

typedef __bf16 bf16;
typedef __bf16 bf16x8 __attribute__((ext_vector_type(8)));
typedef float f32x4 __attribute__((ext_vector_type(4)));

#define HIDDEN 1024
#define HEADS  16
#define HD     64
#define SEQ    2048
#define BATCH  2
#define NTOK   (BATCH*SEQ)
#define E3     (3*HIDDEN)

// softmax scale 1/8 with log2(e) folded in, applied to Q at QKV-GEMM epilogue
#define QSCALE (0.125f * 1.44269504088896f)

#if __has_builtin(__builtin_amdgcn_exp2f)
#define EXP2(x) __builtin_amdgcn_exp2f(x)
#else
#define EXP2(x) __expf((x) * 0.69314718055995f)
#endif

static __device__ __forceinline__ uint32_t pkbf(float a, float b) {
  union { bf16 h[2]; uint32_t u; } x;
  x.h[0] = (bf16)a; x.h[1] = (bf16)b;
  return x.u;
}

// ---------------- f32 -> bf16 convert of x, w_qkv, w_out ----------------
__global__ __launch_bounds__(256) void k_convert(
    const float* __restrict__ x, const float* __restrict__ wqkv, const float* __restrict__ wout,
    bf16* __restrict__ xb, bf16* __restrict__ wqkvb, bf16* __restrict__ woutb)
{
  const int NX = NTOK*HIDDEN/4, NW = E3*HIDDEN/4;
  int i = blockIdx.x*256 + threadIdx.x;
  const float4* s; bf16* d; int o;
  if (i < NX)            { s=(const float4*)x;    d=xb;    o=i; }
  else if (i < NX+NW)    { s=(const float4*)wqkv; d=wqkvb; o=i-NX; }
  else                   { s=(const float4*)wout; d=woutb; o=i-NX-NW; }
  float4 v = s[o];
  union { bf16 b[4]; uint2 u; } p;
  p.b[0]=(bf16)v.x; p.b[1]=(bf16)v.y; p.b[2]=(bf16)v.z; p.b[3]=(bf16)v.w;
  *(uint2*)(d + (size_t)o*4) = p.u;
}

// ---------------- bf16 GEMM  C[M,N] = A[M,K] * B[N,K]^T,  BK=64 ----------------
// LDS rows are 128B -> T2 XOR swizzle: chunk c of row r stored at c^(r&7)
// (pre-swizzled global source, linear LDS dest for global_load_lds; XOR on read).
// EPI=0: scatter to Q/K/V head layout (Q scaled by QSCALE).  EPI=1: f32 out.
template<int EPI, int BM>
__global__ __launch_bounds__(256) void k_gemm(
    const bf16* __restrict__ A, const bf16* __restrict__ B,
    bf16* __restrict__ Oq, bf16* __restrict__ Ok, bf16* __restrict__ Ov,
    float* __restrict__ Of, int M, int N, int K, int nbn)
{
  constexpr int MI = BM/32;
  __shared__ bf16 As[BM*64];
  __shared__ bf16 Bs[128*64];
  const int t = threadIdx.x;
  const int lane = t & 63;
  const int w = t >> 6;
  const int g = lane >> 4;
  const int l15 = lane & 15;
  const int wm = (w >> 1) * (BM/2), wn = (w & 1) * 64;
  const int bm = blockIdx.x / nbn, bn = blockIdx.x % nbn;
  const int brow = bm*BM, bcol = bn*128;

  f32x4 acc[MI][4];
  #pragma unroll
  for (int mi=0;mi<MI;mi++)
    #pragma unroll
    for (int ni=0;ni<4;ni++)
      #pragma unroll
      for (int r=0;r<4;r++) acc[mi][ni][r] = 0.f;

  const int nk = K >> 6;
  for (int kt = 0; kt < nk; ++kt) {
    // stage A: BM rows x 8 chunks of 16B
    #pragma unroll
    for (int j=0; j<BM/32; j++) {
      int ch = w*(BM*2) + j*64 + lane;
      int row = ch>>3, part = ch&7;
      const bf16* ga = A + (size_t)(brow+row)*K + kt*64 + (part ^ (row&7))*8;
      __builtin_amdgcn_global_load_lds((const uint32_t*)ga,
          (uint32_t*)(As + (size_t)(w*(BM*2) + j*64)*8), 16, 0, 0);
    }
    // stage B: 128 rows x 8 chunks
    #pragma unroll
    for (int j=0; j<4; j++) {
      int ch = w*256 + j*64 + lane;
      int row = ch>>3, part = ch&7;
      const bf16* gb = B + (size_t)(bcol+row)*K + kt*64 + (part ^ (row&7))*8;
      __builtin_amdgcn_global_load_lds((const uint32_t*)gb,
          (uint32_t*)(Bs + (size_t)(w*256 + j*64)*8), 16, 0, 0);
    }
    __syncthreads();
    #pragma unroll
    for (int kc=0; kc<2; kc++) {
      bf16x8 af[MI], bfr[4];
      #pragma unroll
      for (int mi=0;mi<MI;mi++) {
        int row = wm + mi*16 + l15;
        af[mi] = *(const bf16x8*)((const char*)As + row*128 + ((kc*64 + g*16) ^ ((row&7)<<4)));
      }
      #pragma unroll
      for (int ni=0;ni<4;ni++) {
        int row = wn + ni*16 + l15;
        bfr[ni] = *(const bf16x8*)((const char*)Bs + row*128 + ((kc*64 + g*16) ^ ((row&7)<<4)));
      }
      #pragma unroll
      for (int mi=0;mi<MI;mi++)
        #pragma unroll
        for (int ni=0;ni<4;ni++)
          acc[mi][ni] = __builtin_amdgcn_mfma_f32_16x16x32_bf16(af[mi], bfr[ni], acc[mi][ni], 0, 0, 0);
    }
    __syncthreads();
  }

  #pragma unroll
  for (int mi=0;mi<MI;mi++) {
    #pragma unroll
    for (int ni=0;ni<4;ni++) {
      #pragma unroll
      for (int r=0;r<4;r++) {
        float val = acc[mi][ni][r];
        int m = brow + wm + mi*16 + 4*g + r;
        int e = bcol + wn + ni*16 + l15;
        if (EPI == 0) {
          int part = e >> 10, we = e & 1023;
          int hh = we >> 6, dd = we & 63;
          int b = m >> 11, sb = m & 2047;
          size_t idx = (((size_t)b*HEADS + hh)*SEQ + sb)*HD + dd;
          if (part == 0)      Oq[idx] = (bf16)(val * QSCALE);
          else if (part == 1) Ok[idx] = (bf16)val;
          else                Ov[idx] = (bf16)val;
        } else {
          Of[(size_t)m*HIDDEN + e] = val;
        }
      }
    }
  }
}

// ---------------- flash attention, 32 q-rows/wave, T15 2-tile pipeline ----------------
// grid: 32 bh * 16 qblocks; 4 waves/block. Double-buffered K/V LDS; per phase:
// QK-MFMA(tile i) then softmax+PV(tile i-1) -> MFMA/VALU overlap within the wave.
// Reg-staged K/V with early issue (T14). Named score buffers sfA/sfB (unroll-by-2).
__global__ __launch_bounds__(256, 2) void k_attn(
    const bf16* __restrict__ Qg, const bf16* __restrict__ Kg, const bf16* __restrict__ Vg,
    bf16* __restrict__ Og)
{
  __shared__ bf16 Kl[2][64*64];   // [kv][d] 128B rows, 16B-chunk XOR swizzle by (row&7)
  __shared__ bf16 Vt[2][64*64];   // [d][pos] 128B rows, pos = kv-permuted, same swizzle
  const int t = threadIdx.x;
  const int lane = t & 63;
  const int w = t >> 6;
  const int g = lane >> 4;      // 0..3
  const int q = lane & 15;      // this lane's q row (within 16-row q-set)
  const int bh = blockIdx.x >> 4;
  const int qb = blockIdx.x & 15;
  const int q0 = qb*128 + w*32;
  const size_t bhS = (size_t)bh * SEQ * HD;

  // Q fragments (B-operand): k-slot 8g+j of chunk kc -> d = 32kc + 8g + j
  bf16x8 qf[2][2];
  #pragma unroll
  for (int qs=0;qs<2;qs++) {
    const bf16* qrow = Qg + bhS + (size_t)(q0 + 16*qs + q)*HD + 8*g;
    qf[qs][0] = *(const bf16x8*)(qrow);
    qf[qs][1] = *(const bf16x8*)(qrow + 32);
  }

  f32x4 ot[2][4];              // O^T[d = 16df+4g+r][q], per q-set
  #pragma unroll
  for (int qs=0;qs<2;qs++)
    #pragma unroll
    for (int df=0;df<4;df++)
      #pragma unroll
      for (int r=0;r<4;r++) ot[qs][df][r] = 0.f;
  float mrun0 = -3.0e38f, mrun1 = -3.0e38f, lrun0 = 0.f, lrun1 = 0.f;

  // K staging: thread t handles 16B chunks (row=t>>3, part=t&7) and (+32 rows)
  const int kr0 = t >> 3, kp0 = t & 7;
  // V staging: thread handles kv pair (kv0,kv0+1) x 8 d's; permuted column pos0
  const int kv0 = (t & 31)*2;
  const int dd0 = (t >> 5)*8;
  const int kvf0 = kv0 >> 4, gv = (kv0 >> 2) & 3, rv = kv0 & 3;
  const int pos0 = 32*(kvf0 >> 1) + 8*gv + 4*(kvf0 & 1) + rv;   // even

  auto loadK = [&](int it, uint4& a, uint4& b) {
    const bf16* p0 = Kg + bhS + (size_t)(it*64 + kr0)*HD + kp0*8;
    a = *(const uint4*)p0;
    b = *(const uint4*)(p0 + 32*HD);
  };
  auto writeK = [&](int buf, uint4 a, uint4 b) {
    int sw = (kp0 ^ (kr0 & 7)) * 16;          // (kr0+32)&7 == kr0&7
    char* base = (char*)&Kl[buf][0];
    *(uint4*)(base + kr0*128 + sw) = a;
    *(uint4*)(base + (kr0+32)*128 + sw) = b;
  };
  auto loadV = [&](int it, uint4& a, uint4& b) {
    const bf16* vg = Vg + bhS + (size_t)(it*64 + kv0)*HD + dd0;
    a = *(const uint4*)vg;
    b = *(const uint4*)(vg + HD);
  };
  auto writeVt = [&](int buf, uint4 va, uint4 vb) {
    const uint32_t* pa = (const uint32_t*)&va;
    const uint32_t* pb = (const uint32_t*)&vb;
    char* base = (char*)&Vt[buf][0];
    #pragma unroll
    for (int jj=0;jj<8;jj++) {
      int dd = dd0 + jj;                       // dd&7 == jj
      uint32_t pr = __builtin_amdgcn_perm(pb[jj>>1], pa[jj>>1],
                                          (jj&1) ? 0x07060302u : 0x05040100u);
      int byte = (dd*128 + pos0*2) ^ (jj<<4);
      *(uint32_t*)(base + byte) = pr;
    }
  };

  auto doQK = [&](const char* Kbase, f32x4 (&sf)[2][4]) {
    #pragma unroll
    for (int qs=0;qs<2;qs++)
      #pragma unroll
      for (int kvf=0;kvf<4;kvf++)
        #pragma unroll
        for (int r=0;r<4;r++) sf[qs][kvf][r] = 0.f;
    __builtin_amdgcn_s_setprio(1);
    #pragma unroll
    for (int kvf=0;kvf<4;kvf++) {
      int row = 16*kvf + q;
      #pragma unroll
      for (int kc=0;kc<2;kc++) {
        int byte = row*128 + ((16*g + 64*kc) ^ ((row&7)<<4));
        bf16x8 kf = *(const bf16x8*)(Kbase + byte);
        sf[0][kvf] = __builtin_amdgcn_mfma_f32_16x16x32_bf16(kf, qf[0][kc], sf[0][kvf], 0,0,0);
        sf[1][kvf] = __builtin_amdgcn_mfma_f32_16x16x32_bf16(kf, qf[1][kc], sf[1][kvf], 0,0,0);
      }
    }
    __builtin_amdgcn_s_setprio(0);
  };

  auto doSMPV = [&](const char* Vbase, f32x4 (&sf)[2][4]) {
    float pm0 = -3.0e38f, pm1 = -3.0e38f;
    #pragma unroll
    for (int kvf=0;kvf<4;kvf++)
      #pragma unroll
      for (int r=0;r<4;r++) {
        pm0 = fmaxf(pm0, sf[0][kvf][r]);
        pm1 = fmaxf(pm1, sf[1][kvf][r]);
      }
    pm0 = fmaxf(pm0, __shfl_xor(pm0, 16, 64));
    pm0 = fmaxf(pm0, __shfl_xor(pm0, 32, 64));
    pm1 = fmaxf(pm1, __shfl_xor(pm1, 16, 64));
    pm1 = fmaxf(pm1, __shfl_xor(pm1, 32, 64));

    bool need = (pm0 - mrun0 > 8.f) || (pm1 - mrun1 > 8.f);
    if (__any(need)) {           // defer-max: rescale only on significant growth
      float mn0 = fmaxf(mrun0, pm0), mn1 = fmaxf(mrun1, pm1);
      float a0 = EXP2(mrun0 - mn0), a1 = EXP2(mrun1 - mn1);
      lrun0 *= a0; lrun1 *= a1;
      #pragma unroll
      for (int df=0;df<4;df++)
        #pragma unroll
        for (int r=0;r<4;r++) { ot[0][df][r] *= a0; ot[1][df][r] *= a1; }
      mrun0 = mn0; mrun1 = mn1;
    }
    float rs0 = 0.f, rs1 = 0.f;
    #pragma unroll
    for (int kvf=0;kvf<4;kvf++)
      #pragma unroll
      for (int r=0;r<4;r++) {
        float p0 = EXP2(sf[0][kvf][r] - mrun0); sf[0][kvf][r] = p0; rs0 += p0;
        float p1 = EXP2(sf[1][kvf][r] - mrun1); sf[1][kvf][r] = p1; rs1 += p1;
      }
    rs0 += __shfl_xor(rs0, 16, 64); rs0 += __shfl_xor(rs0, 32, 64);
    rs1 += __shfl_xor(rs1, 16, 64); rs1 += __shfl_xor(rs1, 32, 64);
    lrun0 += rs0; lrun1 += rs1;

    uint32_t pk[2][4][2];
    #pragma unroll
    for (int qs=0;qs<2;qs++)
      #pragma unroll
      for (int kvf=0;kvf<4;kvf++) {
        pk[qs][kvf][0] = pkbf(sf[qs][kvf][0], sf[qs][kvf][1]);
        pk[qs][kvf][1] = pkbf(sf[qs][kvf][2], sf[qs][kvf][3]);
      }

    __builtin_amdgcn_s_setprio(1);
    #pragma unroll
    for (int kc=0;kc<2;kc++) {
      union { uint32_t u[4]; bf16x8 v; } pf0, pf1;
      pf0.u[0] = pk[0][2*kc][0]; pf0.u[1] = pk[0][2*kc][1];
      pf0.u[2] = pk[0][2*kc+1][0]; pf0.u[3] = pk[0][2*kc+1][1];
      pf1.u[0] = pk[1][2*kc][0]; pf1.u[1] = pk[1][2*kc][1];
      pf1.u[2] = pk[1][2*kc+1][0]; pf1.u[3] = pk[1][2*kc+1][1];
      #pragma unroll
      for (int df=0;df<4;df++) {
        int row = 16*df + q;
        int byte = row*128 + ((16*g + 64*kc) ^ ((row&7)<<4));
        bf16x8 vf = *(const bf16x8*)(Vbase + byte);
        ot[0][df] = __builtin_amdgcn_mfma_f32_16x16x32_bf16(vf, pf0.v, ot[0][df], 0,0,0);
        ot[1][df] = __builtin_amdgcn_mfma_f32_16x16x32_bf16(vf, pf1.v, ot[1][df], 0,0,0);
      }
    }
    __builtin_amdgcn_s_setprio(0);
  };

  const char* K0 = (const char*)&Kl[0][0];
  const char* K1 = (const char*)&Kl[1][0];
  const char* V0 = (const char*)&Vt[0][0];
  const char* V1 = (const char*)&Vt[1][0];

  uint4 ka, kb, va, vb;
  // prologue: stage tile 0 into buf0, then preload tile 1 regs
  loadK(0, ka, kb); loadV(0, va, vb);
  writeK(0, ka, kb); writeVt(0, va, vb);
  __syncthreads();
  loadK(1, ka, kb); loadV(1, va, vb);

  f32x4 sfA[2][4], sfB[2][4];
  const int NT = SEQ/64;                 // 32, even
  for (int it = 0; it < NT; it += 2) {
    // phase A: tile it (buf0); finish tile it-1 (buf1)
    doQK(K0, sfA);
    if (it > 0) doSMPV(V1, sfB);
    __syncthreads();                     // buf1 readers done
    writeK(1, ka, kb); writeVt(1, va, vb);   // tile it+1 -> buf1
    __syncthreads();                     // staged
    if (it + 2 < NT) { loadK(it+2, ka, kb); loadV(it+2, va, vb); }
    // phase B: tile it+1 (buf1); finish tile it (buf0)
    doQK(K1, sfB);
    doSMPV(V0, sfA);
    if (it + 2 < NT) {
      __syncthreads();                   // buf0 readers done
      writeK(0, ka, kb); writeVt(0, va, vb); // tile it+2 -> buf0
      __syncthreads();
      if (it + 3 < NT) { loadK(it+3, ka, kb); loadV(it+3, va, vb); }
    }
  }
  doSMPV(V1, sfB);                       // tile NT-1

  // normalize + store O[token][head*64 + d], 8B per (qs,df)
  float inv0 = 1.0f / lrun0, inv1 = 1.0f / lrun1;
  int b = bh >> 4, head = bh & 15;
  #pragma unroll
  for (int qs=0;qs<2;qs++) {
    float inv = qs ? inv1 : inv0;
    size_t orow = ((size_t)b*SEQ + q0 + 16*qs + q)*HIDDEN + head*HD;
    #pragma unroll
    for (int df=0;df<4;df++) {
      uint2 pr;
      pr.x = pkbf(ot[qs][df][0]*inv, ot[qs][df][1]*inv);
      pr.y = pkbf(ot[qs][df][2]*inv, ot[qs][df][3]*inv);
      *(uint2*)(Og + orow + 16*df + 4*g) = pr;
    }
  }
}

extern "C" void kernel_launch(void* const* d_in, const int* in_sizes, int n_in,
                              void* d_out, int out_size, void* d_ws, size_t ws_size,
                              hipStream_t stream)
{
  (void)in_sizes; (void)n_in; (void)out_size; (void)ws_size;
  const float* x    = (const float*)d_in[0];
  const float* wqkv = (const float*)d_in[1];
  const float* wout = (const float*)d_in[2];
  float* out = (float*)d_out;
  char* ws = (char*)d_ws;
  bf16* xb    = (bf16*)(ws);                 //  8 MiB  [4096][1024]
  bf16* wqkvb = (bf16*)(ws + 8388608);       //  6 MiB  [3072][1024]
  bf16* woutb = (bf16*)(ws + 14680064);      //  2 MiB  [1024][1024]
  bf16* Q     = (bf16*)(ws + 16777216);      //  8 MiB  [2][16][2048][64] (pre-scaled QSCALE)
  bf16* K     = (bf16*)(ws + 25165824);      //  8 MiB
  bf16* V     = (bf16*)(ws + 33554432);      //  8 MiB
  bf16* O     = (bf16*)(ws + 41943040);      //  8 MiB  [4096][1024]

  k_convert<<<8192, 256, 0, stream>>>(x, wqkv, wout, xb, wqkvb, woutb);
  k_gemm<0,128><<<32*24, 256, 0, stream>>>(xb, wqkvb, Q, K, V, nullptr, NTOK, E3, HIDDEN, 24);
  k_attn<<<512, 256, 0, stream>>>(Q, K, V, O);
  k_gemm<1,64><<<64*8, 256, 0, stream>>>(O, woutb, nullptr, nullptr, nullptr, out, NTOK, HIDDEN, HIDDEN, 8);
}